// Round 2
// baseline (1412.516 us; speedup 1.0000x reference)
//
#include <hip/hip_runtime.h>

typedef __attribute__((ext_vector_type(8))) _Float16 f16x8;
typedef __attribute__((ext_vector_type(4))) float f32x4;

#define NB 512
#define NH 3
#define NSEQ 344   // 343 + 1 global token
#define NPAD 352   // padded rows per (b,h) slice in ws
#define NX 343
#define HD 32
#define CDIM 96
#define SCALE 0.17677669529663687f  // 1/sqrt(32)

static __device__ __forceinline__ unsigned short f2h(float f) {
    _Float16 h = (_Float16)f;
    return __builtin_bit_cast(unsigned short, h);
}
static __device__ __forceinline__ f16x8 ld8(const unsigned short* p) {
    uint4 u = *(const uint4*)p;
    return __builtin_bit_cast(f16x8, u);
}

// ---------------- K0: bias gather -> biasm[h][343][343] fp32 ----------------
__global__ void k_bias(const int* __restrict__ rel, const float* __restrict__ table,
                       float* __restrict__ biasm) {
    int idx = blockIdx.x * 256 + threadIdx.x;
    if (idx < NX * NX) {
        int r = rel[idx];
        biasm[idx]              = table[r * 3 + 0];
        biasm[NX * NX + idx]    = table[r * 3 + 1];
        biasm[2 * NX * NX + idx] = table[r * 3 + 2];
    }
}

// ---------------- K1: QKV GEMM (176128 x 288, K=96) -------------------------
__global__ __launch_bounds__(256) void k_qkv(
    const float* __restrict__ x, const float* __restrict__ gt,
    const float* __restrict__ Wqkv, const float* __restrict__ bqkv,
    unsigned short* __restrict__ qs, unsigned short* __restrict__ ks,
    unsigned short* __restrict__ vs)
{
    __shared__ unsigned short Wb[288 * 104];  // 59.9 KB, stride 104 -> 2-way banks (free), rows 16B aligned
    int tid = threadIdx.x;
    for (int i = tid; i < 288 * 96; i += 256) {
        int c = i / 96, k = i - c * 96;
        Wb[c * 104 + k] = f2h(Wqkv[i]);
    }
    __syncthreads();
    int w = tid >> 6, l = tid & 63, la = l & 15, lg = l >> 4;

    // A fragment: row = la, k = kk*32 + lg*8 .. +7, straight from global fp32
    int rowA = blockIdx.x * 64 + w * 16 + la;           // < 176128 exactly
    int bA = rowA / NSEQ, nA = rowA - bA * NSEQ;
    const float* srcA = (nA == 0) ? (gt + bA * CDIM) : (x + (bA * NX + (nA - 1)) * CDIM);
    f16x8 af[3];
#pragma unroll
    for (int kk = 0; kk < 3; ++kk) {
        float4 f0 = *(const float4*)&srcA[kk * 32 + lg * 8];
        float4 f1 = *(const float4*)&srcA[kk * 32 + lg * 8 + 4];
        f16x8 a;
        a[0] = (_Float16)f0.x; a[1] = (_Float16)f0.y; a[2] = (_Float16)f0.z; a[3] = (_Float16)f0.w;
        a[4] = (_Float16)f1.x; a[5] = (_Float16)f1.y; a[6] = (_Float16)f1.z; a[7] = (_Float16)f1.w;
        af[kk] = a;
    }
    f32x4 acc[18];
#pragma unroll
    for (int t = 0; t < 18; ++t) { acc[t][0]=0.f; acc[t][1]=0.f; acc[t][2]=0.f; acc[t][3]=0.f; }
#pragma unroll
    for (int t = 0; t < 18; ++t) {
#pragma unroll
        for (int kk = 0; kk < 3; ++kk) {
            f16x8 bf = ld8(&Wb[(t * 16 + la) * 104 + kk * 32 + lg * 8]);
            acc[t] = __builtin_amdgcn_mfma_f32_16x16x32_f16(af[kk], bf, acc[t], 0, 0, 0);
        }
    }
    // epilogue: C row = lg*4 + r, col = t*16 + la
    int rowBase = blockIdx.x * 64 + w * 16 + lg * 4;
#pragma unroll
    for (int t = 0; t < 18; ++t) {
        int c = t * 16 + la;
        int s = c / 96;
        int rem = c - s * 96;
        int h = rem >> 5, d = rem & 31;
        float bq = bqkv[c];
        unsigned short* dst = (s == 0) ? qs : ((s == 1) ? ks : vs);
        float mul = (s == 0) ? SCALE : 1.0f;
#pragma unroll
        for (int r = 0; r < 4; ++r) {
            int row = rowBase + r;
            int b = row / NSEQ, n = row - b * NSEQ;
            float v = (acc[t][r] + bq) * mul;
            dst[((b * NH + h) * NPAD + n) * HD + d] = f2h(v);
        }
    }
}

// ---------------- K2: attention, one block per (b,h) ------------------------
__global__ __launch_bounds__(256) void k_attn(
    const unsigned short* __restrict__ qs, const unsigned short* __restrict__ ks,
    const unsigned short* __restrict__ vs, const float* __restrict__ mask,
    const float* __restrict__ biasm, unsigned short* __restrict__ ao)
{
    __shared__ unsigned short Vt[32 * 360];       // 23.0 KB, V transposed [d][n]
    __shared__ unsigned short Pl[4 * 16 * 264];   // 33.8 KB, per-wave P (two phases)

    // XCD swizzle: blocks sharing a mask window land on one XCD, contiguous in time
    int L = blockIdx.x;
    int xcd = L & 7; int s0 = L >> 3;
    int w_loc = s0 / 24; int rem = s0 - w_loc * 24;
    int grp = rem / 3;  int h = rem - grp * 3;
    int wm = xcd + 8 * w_loc;         // mask window index = b % 64
    int b = wm + 64 * grp;

    int tid = threadIdx.x;
    int slice = (b * NH + h) * NPAD;
    const unsigned short* qb = qs + (size_t)slice * HD;
    const unsigned short* kb = ks + (size_t)slice * HD;
    const unsigned short* vb = vs + (size_t)slice * HD;

    // stage V transposed: Vt[d][n] = v[n][d]
    for (int ch = tid; ch < NSEQ * 4; ch += 256) {
        int n = ch >> 2, dq = ch & 3;
        uint4 raw = *(const uint4*)&vb[n * HD + dq * 8];
        unsigned int uu[4] = {raw.x, raw.y, raw.z, raw.w};
#pragma unroll
        for (int j = 0; j < 4; ++j) {
            Vt[(dq * 8 + 2 * j) * 360 + n]     = (unsigned short)(uu[j] & 0xffffu);
            Vt[(dq * 8 + 2 * j + 1) * 360 + n] = (unsigned short)(uu[j] >> 16);
        }
    }
    for (int i2 = tid; i2 < 32 * 8; i2 += 256) {   // zero the 8 pad columns
        int d = i2 >> 3, n = NSEQ + (i2 & 7);
        Vt[d * 360 + n] = 0;
    }
    __syncthreads();

    int w = tid >> 6, l = tid & 63, la = l & 15, lg = l >> 4;
    unsigned short* Pw = Pl + w * 16 * 264;
    const float* mrow = mask + (size_t)wm * NX * NX;
    const float* brow = biasm + (size_t)h * NX * NX;

    for (int qt = 0; qt < 6; ++qt) {
        int qrow0 = qt * 64 + w * 16;
        if (qrow0 >= NSEQ) continue;               // wave-uniform, no barriers inside loop
        int qr = qrow0 + la; if (qr > NX) qr = NX; // clamp tail rows (results discarded)
        f16x8 aq = ld8(&qb[qr * HD + lg * 8]);

        // scores: S[qrow0 + lg*4+r][t*16+la]
        f32x4 sc[22];
        f32x4 zero4; zero4[0]=0.f; zero4[1]=0.f; zero4[2]=0.f; zero4[3]=0.f;
#pragma unroll
        for (int t = 0; t < 22; ++t) {
            f16x8 bk = ld8(&kb[(t * 16 + la) * HD + lg * 8]);
            sc[t] = __builtin_amdgcn_mfma_f32_16x16x32_f16(aq, bk, zero4, 0, 0, 0);
        }
        // bias + mask (only i>=1 && j>=1), -inf for pad cols
#pragma unroll
        for (int t = 0; t < 22; ++t) {
            int j = t * 16 + la;
            if (j >= NSEQ) {
                sc[t][0] = -__builtin_inff(); sc[t][1] = -__builtin_inff();
                sc[t][2] = -__builtin_inff(); sc[t][3] = -__builtin_inff();
            } else if (j >= 1) {
                int joff = j - 1;
#pragma unroll
                for (int r = 0; r < 4; ++r) {
                    int i = qrow0 + lg * 4 + r;
                    if (i >= 1 && i < NSEQ) {
                        int off = (i - 1) * NX + joff;
                        sc[t][r] += mrow[off] + brow[off];
                    }
                }
            }
        }
        // exact softmax: reduce over 22 in-lane values x 16 lanes (shfl_xor 1,2,4,8)
        float sm[4];
#pragma unroll
        for (int r = 0; r < 4; ++r) {
            float m = sc[0][r];
#pragma unroll
            for (int t = 1; t < 22; ++t) m = fmaxf(m, sc[t][r]);
            m = fmaxf(m, __shfl_xor(m, 1));
            m = fmaxf(m, __shfl_xor(m, 2));
            m = fmaxf(m, __shfl_xor(m, 4));
            m = fmaxf(m, __shfl_xor(m, 8));
            float ssum = 0.f;
#pragma unroll
            for (int t = 0; t < 22; ++t) {
                float p = __expf(sc[t][r] - m);
                sc[t][r] = p;
                ssum += p;
            }
            ssum += __shfl_xor(ssum, 1);
            ssum += __shfl_xor(ssum, 2);
            ssum += __shfl_xor(ssum, 4);
            ssum += __shfl_xor(ssum, 8);
            sm[r] = ssum;
        }
        // PV in two phases through per-wave LDS (DS ops are wave-ordered; no barrier)
        f32x4 o0 = zero4, o1 = zero4;
#pragma unroll
        for (int t = 0; t < 16; ++t)
#pragma unroll
            for (int r = 0; r < 4; ++r)
                Pw[(lg * 4 + r) * 264 + t * 16 + la] = f2h(sc[t][r]);
#pragma unroll
        for (int ksl = 0; ksl < 8; ++ksl) {
            f16x8 ap  = ld8(&Pw[la * 264 + ksl * 32 + lg * 8]);
            f16x8 bv0 = ld8(&Vt[la * 360 + ksl * 32 + lg * 8]);
            f16x8 bv1 = ld8(&Vt[(16 + la) * 360 + ksl * 32 + lg * 8]);
            o0 = __builtin_amdgcn_mfma_f32_16x16x32_f16(ap, bv0, o0, 0, 0, 0);
            o1 = __builtin_amdgcn_mfma_f32_16x16x32_f16(ap, bv1, o1, 0, 0, 0);
        }
#pragma unroll
        for (int t = 16; t < 22; ++t)
#pragma unroll
            for (int r = 0; r < 4; ++r)
                Pw[(lg * 4 + r) * 264 + (t - 16) * 16 + la] = f2h(sc[t][r]);
#pragma unroll
        for (int ksl = 8; ksl < 11; ++ksl) {
            f16x8 ap  = ld8(&Pw[la * 264 + (ksl - 8) * 32 + lg * 8]);
            f16x8 bv0 = ld8(&Vt[la * 360 + ksl * 32 + lg * 8]);
            f16x8 bv1 = ld8(&Vt[(16 + la) * 360 + ksl * 32 + lg * 8]);
            o0 = __builtin_amdgcn_mfma_f32_16x16x32_f16(ap, bv0, o0, 0, 0, 0);
            o1 = __builtin_amdgcn_mfma_f32_16x16x32_f16(ap, bv1, o1, 0, 0, 0);
        }
        // write O/rowsum (rows of O share the softmax-sum lane mapping)
#pragma unroll
        for (int r = 0; r < 4; ++r) {
            int i = qrow0 + lg * 4 + r;
            if (i < NSEQ) {
                float inv = 1.0f / sm[r];
                size_t o_off = ((size_t)b * NSEQ + i) * CDIM + h * HD;
                ao[o_off + la]      = f2h(o0[r] * inv);
                ao[o_off + 16 + la] = f2h(o1[r] * inv);
            }
        }
    }
}

// ---------------- K3: output projection (176128 x 96, K=96) -----------------
__global__ __launch_bounds__(256) void k_proj(
    const unsigned short* __restrict__ ao, const float* __restrict__ Wproj,
    const float* __restrict__ bproj, float* __restrict__ out)
{
    __shared__ unsigned short Wb[96 * 104];
    int tid = threadIdx.x;
    for (int i = tid; i < 96 * 96; i += 256) {
        int c = i / 96, k = i - c * 96;
        Wb[c * 104 + k] = f2h(Wproj[i]);
    }
    __syncthreads();
    int w = tid >> 6, l = tid & 63, la = l & 15, lg = l >> 4;
    int rowA = blockIdx.x * 64 + w * 16 + la;
    f16x8 af[3];
#pragma unroll
    for (int kk = 0; kk < 3; ++kk)
        af[kk] = ld8(&ao[(size_t)rowA * CDIM + kk * 32 + lg * 8]);
    f32x4 acc[6];
#pragma unroll
    for (int t = 0; t < 6; ++t) { acc[t][0]=0.f; acc[t][1]=0.f; acc[t][2]=0.f; acc[t][3]=0.f; }
#pragma unroll
    for (int t = 0; t < 6; ++t)
#pragma unroll
        for (int kk = 0; kk < 3; ++kk) {
            f16x8 bf = ld8(&Wb[(t * 16 + la) * 104 + kk * 32 + lg * 8]);
            acc[t] = __builtin_amdgcn_mfma_f32_16x16x32_f16(af[kk], bf, acc[t], 0, 0, 0);
        }
    int rowBase = blockIdx.x * 64 + w * 16 + lg * 4;
#pragma unroll
    for (int t = 0; t < 6; ++t) {
        int c = t * 16 + la;
        float bp = bproj[c];
#pragma unroll
        for (int r = 0; r < 4; ++r) {
            int row = rowBase + r;
            int b = row / NSEQ, n = row - b * NSEQ;
            float v = acc[t][r] + bp;
            float* dst = (n == 0) ? (out + (size_t)NB * NX * CDIM + (size_t)b * CDIM)
                                  : (out + ((size_t)b * NX + (n - 1)) * CDIM);
            dst[c] = v;
        }
    }
}

extern "C" void kernel_launch(void* const* d_in, const int* in_sizes, int n_in,
                              void* d_out, int out_size, void* d_ws, size_t ws_size,
                              hipStream_t stream) {
    const float* x     = (const float*)d_in[0];
    const float* gt    = (const float*)d_in[1];
    const float* mask  = (const float*)d_in[2];
    const int*   rel   = (const int*)d_in[3];
    const float* Wqkv  = (const float*)d_in[4];
    const float* bqkv  = (const float*)d_in[5];
    const float* Wproj = (const float*)d_in[6];
    const float* bproj = (const float*)d_in[7];
    const float* table = (const float*)d_in[8];
    float* out = (float*)d_out;

    // ws layout (f16 tensors + fp32 bias matrix), ~139 MB total
    size_t qkv_elems = (size_t)NB * NH * NPAD * HD;           // 17,301,504
    unsigned short* qs = (unsigned short*)d_ws;
    unsigned short* ks = qs + qkv_elems;
    unsigned short* vs = ks + qkv_elems;
    unsigned short* ao = vs + qkv_elems;                      // [B][344][96] f16
    float* biasm = (float*)(ao + (size_t)NB * NSEQ * CDIM);   // [3][343][343] f32

    hipLaunchKernelGGL(k_bias, dim3((NX * NX + 255) / 256), dim3(256), 0, stream,
                       rel, table, biasm);
    hipLaunchKernelGGL(k_qkv, dim3(2752), dim3(256), 0, stream,
                       x, gt, Wqkv, bqkv, qs, ks, vs);
    hipLaunchKernelGGL(k_attn, dim3(1536), dim3(256), 0, stream,
                       qs, ks, vs, mask, biasm, ao);
    hipLaunchKernelGGL(k_proj, dim3(2752), dim3(256), 0, stream,
                       ao, Wproj, bproj, out);
    (void)in_sizes; (void)n_in; (void)out_size; (void)ws_size;
}

// Round 3
// 639.027 us; speedup vs baseline: 2.2104x; 2.2104x over previous
//
#include <hip/hip_runtime.h>

typedef __attribute__((ext_vector_type(8))) _Float16 f16x8;
typedef __attribute__((ext_vector_type(4))) float f32x4;

#define NB 512
#define NH 3
#define NSEQ 344   // 343 + 1 global token
#define NPAD 352   // padded rows per (b,h) slice in ws
#define NX 343
#define HD 32
#define CDIM 96
#define SCALE 0.17677669529663687f  // 1/sqrt(32)

static __device__ __forceinline__ unsigned short f2h(float f) {
    _Float16 h = (_Float16)f;
    return __builtin_bit_cast(unsigned short, h);
}
static __device__ __forceinline__ f16x8 ld8(const unsigned short* p) {
    uint4 u = *(const uint4*)p;
    return __builtin_bit_cast(f16x8, u);
}

// ---------------- K0: bias gather -> biasm[h][343][343] fp32 ----------------
__global__ void k_bias(const int* __restrict__ rel, const float* __restrict__ table,
                       float* __restrict__ biasm) {
    int idx = blockIdx.x * 256 + threadIdx.x;
    if (idx < NX * NX) {
        int r = rel[idx];
        biasm[idx]               = table[r * 3 + 0];
        biasm[NX * NX + idx]     = table[r * 3 + 1];
        biasm[2 * NX * NX + idx] = table[r * 3 + 2];
    }
}

// ---------------- K1: QKV GEMM (176128 x 288, K=96) -------------------------
__global__ __launch_bounds__(256) void k_qkv(
    const float* __restrict__ x, const float* __restrict__ gt,
    const float* __restrict__ Wqkv, const float* __restrict__ bqkv,
    unsigned short* __restrict__ qs, unsigned short* __restrict__ ks,
    unsigned short* __restrict__ vs)
{
    __shared__ unsigned short Wb[288 * 104];  // 59.9 KB
    int tid = threadIdx.x;
    for (int i = tid; i < 288 * 96; i += 256) {
        int c = i / 96, k = i - c * 96;
        Wb[c * 104 + k] = f2h(Wqkv[i]);
    }
    __syncthreads();
    int w = tid >> 6, l = tid & 63, la = l & 15, lg = l >> 4;

    int rowA = blockIdx.x * 64 + w * 16 + la;           // < 176128 exactly
    int bA = rowA / NSEQ, nA = rowA - bA * NSEQ;
    const float* srcA = (nA == 0) ? (gt + bA * CDIM) : (x + (bA * NX + (nA - 1)) * CDIM);
    f16x8 af[3];
#pragma unroll
    for (int kk = 0; kk < 3; ++kk) {
        float4 f0 = *(const float4*)&srcA[kk * 32 + lg * 8];
        float4 f1 = *(const float4*)&srcA[kk * 32 + lg * 8 + 4];
        f16x8 a;
        a[0] = (_Float16)f0.x; a[1] = (_Float16)f0.y; a[2] = (_Float16)f0.z; a[3] = (_Float16)f0.w;
        a[4] = (_Float16)f1.x; a[5] = (_Float16)f1.y; a[6] = (_Float16)f1.z; a[7] = (_Float16)f1.w;
        af[kk] = a;
    }
    f32x4 acc[18];
#pragma unroll
    for (int t = 0; t < 18; ++t) { acc[t][0]=0.f; acc[t][1]=0.f; acc[t][2]=0.f; acc[t][3]=0.f; }
#pragma unroll
    for (int t = 0; t < 18; ++t) {
#pragma unroll
        for (int kk = 0; kk < 3; ++kk) {
            f16x8 bf = ld8(&Wb[(t * 16 + la) * 104 + kk * 32 + lg * 8]);
            acc[t] = __builtin_amdgcn_mfma_f32_16x16x32_f16(af[kk], bf, acc[t], 0, 0, 0);
        }
    }
    int rowBase = blockIdx.x * 64 + w * 16 + lg * 4;
#pragma unroll
    for (int t = 0; t < 18; ++t) {
        int c = t * 16 + la;
        int s = c / 96;
        int rem = c - s * 96;
        int h = rem >> 5, d = rem & 31;
        float bq = bqkv[c];
        unsigned short* dst = (s == 0) ? qs : ((s == 1) ? ks : vs);
        float mul = (s == 0) ? SCALE : 1.0f;
#pragma unroll
        for (int r = 0; r < 4; ++r) {
            int row = rowBase + r;
            int b = row / NSEQ, n = row - b * NSEQ;
            float v = (acc[t][r] + bq) * mul;
            dst[((b * NH + h) * NPAD + n) * HD + d] = f2h(v);
        }
    }
}

// ---------------- K2: attention -----------------------------------------------
// 1536 blocks: (xcd,w_loc)->wm, G->batch pair, h, qh->q-tile half.
// Two batches per block share one register-cached mask+bias tile.
__global__ __launch_bounds__(256, 2) void k_attn(
    const unsigned short* __restrict__ qs, const unsigned short* __restrict__ ks,
    const unsigned short* __restrict__ vs, const float* __restrict__ mask,
    const float* __restrict__ biasm, unsigned short* __restrict__ ao)
{
    __shared__ unsigned short Vt[2 * 32 * 360];   // 46.1 KB, V transposed per batch
    __shared__ unsigned short Pl[4 * 16 * 136];   // 17.4 KB, per-wave P chunk

    int L = blockIdx.x;
    int xcd = L & 7; int s0 = L >> 3;             // 0..191
    int w_loc = s0 / 24; int rem = s0 - w_loc * 24;
    int G = rem / 6; int rem2 = rem - G * 6;
    int h = rem2 >> 1; int qh = rem2 & 1;
    int wm = xcd + 8 * w_loc;                     // mask window = b % 64
    int bx0 = wm + 64 * (2 * G);
    int bx1 = wm + 64 * (2 * G + 1);

    int tid = threadIdx.x;

    // stage V transposed for both batches: Vt[bb][d][n]
    for (int bb = 0; bb < 2; ++bb) {
        int b = bb ? bx1 : bx0;
        const unsigned short* vb = vs + (size_t)((b * NH + h) * NPAD) * HD;
        unsigned short* V = Vt + bb * 32 * 360;
        for (int ch = tid; ch < NSEQ * 4; ch += 256) {
            int n = ch >> 2, dq = ch & 3;
            uint4 raw = *(const uint4*)&vb[n * HD + dq * 8];
            unsigned int uu[4] = {raw.x, raw.y, raw.z, raw.w};
#pragma unroll
            for (int j = 0; j < 4; ++j) {
                V[(dq * 8 + 2 * j) * 360 + n]     = (unsigned short)(uu[j] & 0xffffu);
                V[(dq * 8 + 2 * j + 1) * 360 + n] = (unsigned short)(uu[j] >> 16);
            }
        }
        for (int i2 = tid; i2 < 32 * 8; i2 += 256) {   // zero pad cols (avoid NaN garbage)
            V[(i2 >> 3) * 360 + NSEQ + (i2 & 7)] = 0;
        }
    }
    __syncthreads();

    int w = tid >> 6, l = tid & 63, la = l & 15, lg = l >> 4;
    unsigned short* Pw = Pl + w * 16 * 136;
    const float* mrow = mask + (size_t)wm * NX * NX;
    const float* brow = biasm + (size_t)h * NX * NX;

    for (int qt = qh * 3; qt < qh * 3 + 3; ++qt) {
        int qrow0 = qt * 64 + w * 16;
        if (qrow0 >= NSEQ) continue;               // wave-uniform

        // ---- mask+bias tile into registers (reused for both batches) ----
        float mb[22][4];
        int iBase = qrow0 + lg * 4;
#pragma unroll
        for (int t = 0; t < 22; ++t) {
            int j = t * 16 + la;
            bool jok = (j >= 1) && (j < NSEQ);
#pragma unroll
            for (int r = 0; r < 4; ++r) {
                int i = iBase + r;
                float v = 0.f;
                if (jok && i >= 1 && i < NSEQ) {
                    int off = (i - 1) * NX + (j - 1);
                    v = mrow[off] + brow[off];
                }
                mb[t][r] = v;
            }
        }

        for (int bb = 0; bb < 2; ++bb) {
            int b = bb ? bx1 : bx0;
            const unsigned short* qb = qs + (size_t)((b * NH + h) * NPAD) * HD;
            const unsigned short* kb = ks + (size_t)((b * NH + h) * NPAD) * HD;
            const unsigned short* V  = Vt + bb * 32 * 360;

            int qr = qrow0 + la; if (qr > NX) qr = NX;  // clamp tail (discarded)
            f16x8 aq = ld8(&qb[qr * HD + lg * 8]);

            f32x4 zero4; zero4[0]=0.f; zero4[1]=0.f; zero4[2]=0.f; zero4[3]=0.f;
            f32x4 sc[22];
#pragma unroll
            for (int t = 0; t < 22; ++t) {
                f16x8 bk = ld8(&kb[(t * 16 + la) * HD + lg * 8]);
                sc[t] = __builtin_amdgcn_mfma_f32_16x16x32_f16(aq, bk, zero4, 0, 0, 0);
            }
#pragma unroll
            for (int t = 0; t < 22; ++t) {
                int j = t * 16 + la;
                if (j >= NSEQ) {
                    sc[t][0] = -__builtin_inff(); sc[t][1] = -__builtin_inff();
                    sc[t][2] = -__builtin_inff(); sc[t][3] = -__builtin_inff();
                } else {
#pragma unroll
                    for (int r = 0; r < 4; ++r) sc[t][r] += mb[t][r];
                }
            }
            // exact softmax over 22 in-lane values x 16 lanes
            float sm[4];
#pragma unroll
            for (int r = 0; r < 4; ++r) {
                float m = sc[0][r];
#pragma unroll
                for (int t = 1; t < 22; ++t) m = fmaxf(m, sc[t][r]);
                m = fmaxf(m, __shfl_xor(m, 1));
                m = fmaxf(m, __shfl_xor(m, 2));
                m = fmaxf(m, __shfl_xor(m, 4));
                m = fmaxf(m, __shfl_xor(m, 8));
                float ssum = 0.f;
#pragma unroll
                for (int t = 0; t < 22; ++t) {
                    float p = __expf(sc[t][r] - m);
                    sc[t][r] = p;
                    ssum += p;
                }
                ssum += __shfl_xor(ssum, 1);
                ssum += __shfl_xor(ssum, 2);
                ssum += __shfl_xor(ssum, 4);
                ssum += __shfl_xor(ssum, 8);
                sm[r] = ssum;
            }
            // PV in 3 chunks through per-wave LDS (DS ops wave-ordered; no barrier)
            f32x4 o0 = zero4, o1 = zero4;
#pragma unroll
            for (int ph = 0; ph < 3; ++ph) {
                const int tB = ph * 8;
                const int nT = (ph == 2) ? 6 : 8;
                const int nK = (ph == 2) ? 3 : 4;
#pragma unroll
                for (int tt = 0; tt < nT; ++tt)
#pragma unroll
                    for (int r = 0; r < 4; ++r)
                        Pw[(lg * 4 + r) * 136 + tt * 16 + la] = f2h(sc[tB + tt][r]);
#pragma unroll
                for (int kk2 = 0; kk2 < nK; ++kk2) {
                    f16x8 ap  = ld8(&Pw[la * 136 + kk2 * 32 + lg * 8]);
                    f16x8 bv0 = ld8(&V[la * 360 + (ph * 4 + kk2) * 32 + lg * 8]);
                    f16x8 bv1 = ld8(&V[(16 + la) * 360 + (ph * 4 + kk2) * 32 + lg * 8]);
                    o0 = __builtin_amdgcn_mfma_f32_16x16x32_f16(ap, bv0, o0, 0, 0, 0);
                    o1 = __builtin_amdgcn_mfma_f32_16x16x32_f16(ap, bv1, o1, 0, 0, 0);
                }
            }
            // epilogue: stage O tile in LDS, then 1KB-contiguous store to ao[h][b][n][d]
#pragma unroll
            for (int r = 0; r < 4; ++r) {
                float inv = 1.0f / sm[r];
                Pw[(lg * 4 + r) * 32 + la]      = f2h(o0[r] * inv);
                Pw[(lg * 4 + r) * 32 + 16 + la] = f2h(o1[r] * inv);
            }
            int row_g = qrow0 + (l >> 2);
            if (row_g < NSEQ) {
                uint4 d = *(const uint4*)&Pw[l * 8];
                unsigned short* dst = ao + ((size_t)(h * NB + b) * NSEQ + row_g) * HD + (l & 3) * 8;
                *(uint4*)dst = d;
            }
        }
    }
}

// ---------------- K3: output projection (176128 x 96, K=96) -----------------
__global__ __launch_bounds__(256) void k_proj(
    const unsigned short* __restrict__ ao, const float* __restrict__ Wproj,
    const float* __restrict__ bproj, float* __restrict__ out)
{
    __shared__ unsigned short Wb[96 * 104];   // 20.0 KB
    __shared__ float Cs[4][16][100];          // 25.6 KB
    int tid = threadIdx.x;
    for (int i = tid; i < 96 * 96; i += 256) {
        int c = i / 96, k = i - c * 96;
        Wb[c * 104 + k] = f2h(Wproj[i]);
    }
    __syncthreads();
    int w = tid >> 6, l = tid & 63, la = l & 15, lg = l >> 4;
    int rowA = blockIdx.x * 64 + w * 16 + la;
    const size_t HSLAB = (size_t)NB * NSEQ * HD;
    f16x8 af[3];
#pragma unroll
    for (int kk = 0; kk < 3; ++kk)
        af[kk] = ld8(&ao[kk * HSLAB + (size_t)rowA * HD + lg * 8]);
    f32x4 acc[6];
#pragma unroll
    for (int t = 0; t < 6; ++t) { acc[t][0]=0.f; acc[t][1]=0.f; acc[t][2]=0.f; acc[t][3]=0.f; }
#pragma unroll
    for (int t = 0; t < 6; ++t)
#pragma unroll
        for (int kk = 0; kk < 3; ++kk) {
            f16x8 bf = ld8(&Wb[(t * 16 + la) * 104 + kk * 32 + lg * 8]);
            acc[t] = __builtin_amdgcn_mfma_f32_16x16x32_f16(af[kk], bf, acc[t], 0, 0, 0);
        }
    // stage C tile in LDS (per-wave region; DS wave-ordered, no barrier)
#pragma unroll
    for (int t = 0; t < 6; ++t) {
        int c = t * 16 + la;
        float bp = bproj[c];
#pragma unroll
        for (int r = 0; r < 4; ++r)
            Cs[w][lg * 4 + r][c] = acc[t][r] + bp;
    }
    // contiguous float4 stores in out-flat order
    int R0 = blockIdx.x * 64 + w * 16;
    const size_t gt_base = (size_t)NB * NX * CDIM;
#pragma unroll
    for (int k2 = 0; k2 < 6; ++k2) {
        int f4 = k2 * 64 + l;                 // 0..383 float4s of the 16x96 tile
        int rloc = f4 / 24; int c4 = f4 - rloc * 24;
        int R = R0 + rloc; int bA = R / NSEQ; int nA = R - bA * NSEQ;
        float4 val = *(const float4*)&Cs[w][rloc][c4 * 4];
        float* dst = (nA == 0) ? (out + gt_base + (size_t)bA * CDIM + c4 * 4)
                               : (out + ((size_t)bA * NX + (nA - 1)) * CDIM + c4 * 4);
        *(float4*)dst = val;
    }
}

extern "C" void kernel_launch(void* const* d_in, const int* in_sizes, int n_in,
                              void* d_out, int out_size, void* d_ws, size_t ws_size,
                              hipStream_t stream) {
    const float* x     = (const float*)d_in[0];
    const float* gt    = (const float*)d_in[1];
    const float* mask  = (const float*)d_in[2];
    const int*   rel   = (const int*)d_in[3];
    const float* Wqkv  = (const float*)d_in[4];
    const float* bqkv  = (const float*)d_in[5];
    const float* Wproj = (const float*)d_in[6];
    const float* bproj = (const float*)d_in[7];
    const float* table = (const float*)d_in[8];
    float* out = (float*)d_out;

    // ws layout (f16 tensors + fp32 bias matrix), ~139 MB total
    size_t qkv_elems = (size_t)NB * NH * NPAD * HD;           // 17,301,504
    unsigned short* qs = (unsigned short*)d_ws;
    unsigned short* ks = qs + qkv_elems;
    unsigned short* vs = ks + qkv_elems;
    unsigned short* ao = vs + qkv_elems;                      // [H][B][344][32] f16
    float* biasm = (float*)(ao + (size_t)NH * NB * NSEQ * HD);// [3][343][343] f32

    hipLaunchKernelGGL(k_bias, dim3((NX * NX + 255) / 256), dim3(256), 0, stream,
                       rel, table, biasm);
    hipLaunchKernelGGL(k_qkv, dim3(2752), dim3(256), 0, stream,
                       x, gt, Wqkv, bqkv, qs, ks, vs);
    hipLaunchKernelGGL(k_attn, dim3(1536), dim3(256), 0, stream,
                       qs, ks, vs, mask, biasm, ao);
    hipLaunchKernelGGL(k_proj, dim3(2752), dim3(256), 0, stream,
                       ao, Wproj, bproj, out);
    (void)in_sizes; (void)n_in; (void)out_size; (void)ws_size;
}